// Round 2
// baseline (5301.051 us; speedup 1.0000x reference)
//
#include <hip/hip_runtime.h>
#include <hip/hip_bf16.h>
#include <cstddef>

// Problem constants (from reference)
#define NR 50000
#define NS 8192
#define DR 128
#define DSUBJ 64
#define HID 128
#define OUTD 64
#define ERR_E 1000000
#define EHS_E 400000

// ---------------------------------------------------------------------------
// init: deg_r = 1.0 (self loop), cnt_s = 0
__global__ __launch_bounds__(256) void init_deg_cnt(float* __restrict__ deg,
                                                    float* __restrict__ cnt) {
    int i = blockIdx.x * 256 + threadIdx.x;
    if (i < NR) deg[i] = 1.0f;
    if (i < NS) cnt[i] = 0.0f;
}

// count in-degree: deg[dst[e]] += 1
__global__ __launch_bounds__(256) void count_edges(const int* __restrict__ dst,
                                                   float* __restrict__ deg, int E) {
    int e = blockIdx.x * 256 + threadIdx.x;
    if (e < E) atomicAdd(&deg[dst[e]], 1.0f);
}

// ---------------------------------------------------------------------------
// Generic small GEMM: out[M x N] = A[M x K] @ W[K x N] (+ bias) (+ A2[M x K2] @ W2[K2 x N])
// N multiple of 4. One thread computes 4 consecutive cols of one row.
template <int N, int K, int K2, bool BIAS>
__global__ __launch_bounds__(256) void gemm_bias2(const float* __restrict__ A,
                                                  const float* __restrict__ W,
                                                  const float* __restrict__ bias,
                                                  const float* __restrict__ A2,
                                                  const float* __restrict__ W2,
                                                  float* __restrict__ out, int M) {
    constexpr int CG = N / 4;        // col groups per row
    constexpr int ROWS = 256 / CG;   // rows per block
    int tid = threadIdx.x;
    int cg = tid % CG;
    int rl = tid / CG;
    int row = blockIdx.x * ROWS + rl;
    if (row >= M) return;
    int col = cg * 4;

    float4 acc;
    if (BIAS) {
        acc = *(const float4*)(bias + col);
    } else {
        acc.x = acc.y = acc.z = acc.w = 0.0f;
    }

    const float* a = A + (size_t)row * K;
#pragma unroll 4
    for (int k = 0; k < K; ++k) {
        float av = a[k];
        float4 w = *(const float4*)(W + (size_t)k * N + col);
        acc.x += av * w.x;
        acc.y += av * w.y;
        acc.z += av * w.z;
        acc.w += av * w.w;
    }
    if constexpr (K2 > 0) {
        const float* a2 = A2 + (size_t)row * K2;
#pragma unroll 4
        for (int k = 0; k < K2; ++k) {
            float av = a2[k];
            float4 w = *(const float4*)(W2 + (size_t)k * N + col);
            acc.x += av * w.x;
            acc.y += av * w.y;
            acc.z += av * w.z;
            acc.w += av * w.w;
        }
    }
    *(float4*)(out + (size_t)row * N + col) = acc;
}

// ---------------------------------------------------------------------------
// GCN edge scatter: agg[dst] += h[src] * rsqrt(deg[src]*deg[dst]); 32 threads/edge,
// each thread handles 4 consecutive floats (dim = 128).
__global__ __launch_bounds__(256) void gcn_scatter(const float* __restrict__ h,
                                                   const int* __restrict__ src,
                                                   const int* __restrict__ dst,
                                                   const float* __restrict__ deg,
                                                   float* __restrict__ agg, int E) {
    int t = blockIdx.x * 256 + threadIdx.x;
    int e = t >> 5;
    if (e >= E) return;
    int c = (t & 31) * 4;
    int s = src[e];
    int d = dst[e];
    float norm = rsqrtf(deg[s] * deg[d]);
    float4 hv = *(const float4*)(h + (size_t)s * 128 + c);
    float* p = agg + (size_t)d * 128 + c;
    atomicAdd(p + 0, hv.x * norm);
    atomicAdd(p + 1, hv.y * norm);
    atomicAdd(p + 2, hv.z * norm);
    atomicAdd(p + 3, hv.w * norm);
}

// SAGE edge scatter: acc[dst] += xsrc[src]  (dim = 128)
__global__ __launch_bounds__(256) void sage_scatter(const float* __restrict__ xsrc,
                                                    const int* __restrict__ src,
                                                    const int* __restrict__ dst,
                                                    float* __restrict__ acc, int E) {
    int t = blockIdx.x * 256 + threadIdx.x;
    int e = t >> 5;
    if (e >= E) return;
    int c = (t & 31) * 4;
    int s = src[e];
    int d = dst[e];
    float4 hv = *(const float4*)(xsrc + (size_t)s * 128 + c);
    float* p = acc + (size_t)d * 128 + c;
    atomicAdd(p + 0, hv.x);
    atomicAdd(p + 1, hv.y);
    atomicAdd(p + 2, hv.z);
    atomicAdd(p + 3, hv.w);
}

// GCN finalize: out[i] = agg[i] + h[i]/deg[i] + bias   (dim = 128)
__global__ __launch_bounds__(256) void gcn_finalize(const float* __restrict__ agg,
                                                    const float* __restrict__ h,
                                                    const float* __restrict__ deg,
                                                    const float* __restrict__ bias,
                                                    float* __restrict__ out, int n) {
    int t = blockIdx.x * 256 + threadIdx.x;
    int i = t >> 5;
    if (i >= n) return;
    int c = (t & 31) * 4;
    float invd = 1.0f / deg[i];
    float4 a = *(const float4*)(agg + (size_t)i * 128 + c);
    float4 hv = *(const float4*)(h + (size_t)i * 128 + c);
    float4 b4 = *(const float4*)(bias + c);
    float4 o;
    o.x = a.x + hv.x * invd + b4.x;
    o.y = a.y + hv.y * invd + b4.y;
    o.z = a.z + hv.z * invd + b4.z;
    o.w = a.w + hv.w * invd + b4.w;
    *(float4*)(out + (size_t)i * 128 + c) = o;
}

// mean divide in place: acc[i] /= max(cnt[i],1)   (dim = 128)
__global__ __launch_bounds__(256) void mean_div(float* __restrict__ acc,
                                                const float* __restrict__ cnt, int n) {
    int t = blockIdx.x * 256 + threadIdx.x;
    int i = t >> 5;
    if (i >= n) return;
    int c = (t & 31) * 4;
    float inv = 1.0f / fmaxf(cnt[i], 1.0f);
    float4 v = *(const float4*)(acc + (size_t)i * 128 + c);
    v.x *= inv; v.y *= inv; v.z *= inv; v.w *= inv;
    *(float4*)(acc + (size_t)i * 128 + c) = v;
}

// ---------------------------------------------------------------------------
extern "C" void kernel_launch(void* const* d_in, const int* in_sizes, int n_in,
                              void* d_out, int out_size, void* d_ws, size_t ws_size,
                              hipStream_t stream) {
    const float* x_region = (const float*)d_in[0];   // [NR,128]
    const float* x_subject = (const float*)d_in[1];  // [NS,64]
    const int* rr_src = (const int*)d_in[2];
    const int* rr_dst = (const int*)d_in[3];
    const int* hs_src = (const int*)d_in[4];
    const int* hs_dst = (const int*)d_in[5];
    const float* Wg1 = (const float*)d_in[6];
    const float* bg1 = (const float*)d_in[7];
    const float* Wl1 = (const float*)d_in[8];
    const float* bl1 = (const float*)d_in[9];
    const float* Wr1 = (const float*)d_in[10];  // [64,128]
    const float* Wg2 = (const float*)d_in[11];
    const float* bg2 = (const float*)d_in[12];
    const float* Wl2 = (const float*)d_in[13];
    const float* bl2 = (const float*)d_in[14];
    const float* Wr2 = (const float*)d_in[15];  // [128,128]
    const float* Wout = (const float*)d_in[16]; // [128,64]
    const float* bout = (const float*)d_in[17]; // [64]
    float* out = (float*)d_out;

    // workspace layout (floats)
    float* ws = (float*)d_ws;
    float* A = ws;                         // NR*128  (h1, later h2)
    float* B = A + (size_t)NR * 128;       // NR*128  (agg, later r2 in place)
    float* C = B + (size_t)NR * 128;       // NR*128  (r1)
    float* SA = C + (size_t)NR * 128;      // NS*128  (sage acc / mean)
    float* SB = SA + (size_t)NS * 128;     // NS*128  (s1)
    float* SC = SB + (size_t)NS * 128;     // NS*128  (s2)
    float* deg = SC + (size_t)NS * 128;    // NR
    float* cnt = deg + NR;                 // NS

    const int TB = 256;
    // degree / count
    init_deg_cnt<<<(NR + TB - 1) / TB, TB, 0, stream>>>(deg, cnt);
    count_edges<<<(ERR_E + TB - 1) / TB, TB, 0, stream>>>(rr_dst, deg, ERR_E);
    count_edges<<<(EHS_E + TB - 1) / TB, TB, 0, stream>>>(hs_dst, cnt, EHS_E);

    // ---------------- Layer 1 ----------------
    // h1 = x_region @ Wg1  -> A
    gemm_bias2<128, 128, 0, false><<<(NR + 7) / 8, TB, 0, stream>>>(
        x_region, Wg1, nullptr, nullptr, nullptr, A, NR);
    // agg1 -> B
    hipMemsetAsync(B, 0, (size_t)NR * 128 * sizeof(float), stream);
    gcn_scatter<<<(ERR_E * 32 + TB - 1) / TB, TB, 0, stream>>>(A, rr_src, rr_dst, deg, B, ERR_E);
    // r1 = B + A/deg + bg1 -> C
    gcn_finalize<<<(NR * 32 + TB - 1) / TB, TB, 0, stream>>>(B, A, deg, bg1, C, NR);

    // SAGE1: mean of x_region over hs edges -> SA
    hipMemsetAsync(SA, 0, (size_t)NS * 128 * sizeof(float), stream);
    sage_scatter<<<(EHS_E * 32 + TB - 1) / TB, TB, 0, stream>>>(x_region, hs_src, hs_dst, SA, EHS_E);
    mean_div<<<(NS * 32 + TB - 1) / TB, TB, 0, stream>>>(SA, cnt, NS);
    // s1 = SA @ Wl1 + bl1 + x_subject @ Wr1 -> SB
    gemm_bias2<128, 128, 64, true><<<(NS + 7) / 8, TB, 0, stream>>>(
        SA, Wl1, bl1, x_subject, Wr1, SB, NS);

    // ---------------- Layer 2 ----------------
    // h2 = r1 @ Wg2 -> A
    gemm_bias2<128, 128, 0, false><<<(NR + 7) / 8, TB, 0, stream>>>(
        C, Wg2, nullptr, nullptr, nullptr, A, NR);
    // agg2 -> B
    hipMemsetAsync(B, 0, (size_t)NR * 128 * sizeof(float), stream);
    gcn_scatter<<<(ERR_E * 32 + TB - 1) / TB, TB, 0, stream>>>(A, rr_src, rr_dst, deg, B, ERR_E);
    // r2 = B + A/deg + bg2 -> B (in place: elementwise)
    gcn_finalize<<<(NR * 32 + TB - 1) / TB, TB, 0, stream>>>(B, A, deg, bg2, B, NR);

    // SAGE2: mean of r1 (C) over hs edges -> SA
    hipMemsetAsync(SA, 0, (size_t)NS * 128 * sizeof(float), stream);
    sage_scatter<<<(EHS_E * 32 + TB - 1) / TB, TB, 0, stream>>>(C, hs_src, hs_dst, SA, EHS_E);
    mean_div<<<(NS * 32 + TB - 1) / TB, TB, 0, stream>>>(SA, cnt, NS);
    // s2 = SA @ Wl2 + bl2 + s1 @ Wr2 -> SC
    gemm_bias2<128, 128, 128, true><<<(NS + 7) / 8, TB, 0, stream>>>(
        SA, Wl2, bl2, SB, Wr2, SC, NS);

    // ---------------- Output ----------------
    // out[0:NR*64]      = r2 @ Wout + bout
    gemm_bias2<64, 128, 0, true><<<(NR + 15) / 16, TB, 0, stream>>>(
        B, Wout, bout, nullptr, nullptr, out, NR);
    // out[NR*64 : end]  = s2 @ Wout + bout
    gemm_bias2<64, 128, 0, true><<<(NS + 15) / 16, TB, 0, stream>>>(
        SC, Wout, bout, nullptr, nullptr, out + (size_t)NR * 64, NS);
}

// Round 4
// 960.946 us; speedup vs baseline: 5.5165x; 5.5165x over previous
//
#include <hip/hip_runtime.h>
#include <hip/hip_bf16.h>
#include <cstddef>

// Problem constants (from reference)
#define NR 50000
#define NS 8192
#define DR 128
#define DSUBJ 64
#define HID 128
#define OUTD 64
#define ERR_E 1000000
#define EHS_E 400000

// ---------------------------------------------------------------------------
// count in-degree (int): cnt[dst[e]] += 1
__global__ __launch_bounds__(256) void count_edges_i(const int* __restrict__ dst,
                                                     int* __restrict__ cnt, int E) {
    int e = blockIdx.x * 256 + threadIdx.x;
    if (e < E) atomicAdd(&cnt[dst[e]], 1);
}

// Single-block scan: rowptr[i+1] = prefix(cnt), cursor[i] = exclusive prefix,
// scale[i] = MODE0: rsqrt(cnt+1) (GCN dinv) / MODE1: 1/max(cnt,1) (SAGE inv-count).
// cnt and cursor are the SAME array (read count, overwrite with exclusive prefix).
template <int MODE>
__global__ __launch_bounds__(1024) void scan_build(int* __restrict__ cnt_cursor,
                                                   int* __restrict__ rowptr,
                                                   float* __restrict__ scale, int n) {
    __shared__ int s[1024];
    __shared__ int carry;
    int tid = threadIdx.x;
    if (tid == 0) { carry = 0; rowptr[0] = 0; }
    __syncthreads();
    for (int base = 0; base < n; base += 1024) {
        int i = base + tid;
        int v = (i < n) ? cnt_cursor[i] : 0;
        s[tid] = v;
        __syncthreads();
#pragma unroll
        for (int off = 1; off < 1024; off <<= 1) {
            int t = (tid >= off) ? s[tid - off] : 0;
            __syncthreads();
            s[tid] += t;
            __syncthreads();
        }
        int incl = s[tid];
        int c = carry;
        if (i < n) {
            rowptr[i + 1] = c + incl;
            cnt_cursor[i] = c + incl - v;   // exclusive prefix = fill cursor
            if (MODE == 0) scale[i] = rsqrtf((float)(v + 1));
            else           scale[i] = 1.0f / fmaxf((float)v, 1.0f);
        }
        __syncthreads();
        if (tid == 0) carry = c + s[1023];
        __syncthreads();
    }
}

// fill CSR column array: col[cursor[dst[e]]++] = src[e]
__global__ __launch_bounds__(256) void fill_csr(const int* __restrict__ src,
                                                const int* __restrict__ dst,
                                                int* __restrict__ cursor,
                                                int* __restrict__ col, int E) {
    int e = blockIdx.x * 256 + threadIdx.x;
    if (e < E) {
        int p = atomicAdd(&cursor[dst[e]], 1);
        col[p] = src[e];
    }
}

// ---------------------------------------------------------------------------
// Generic small GEMM: out[M x N] = A[M x K] @ W[K x N] (+ bias) (+ A2[M x K2] @ W2[K2 x N])
// optionally scaled per-row by rs[row]. One thread computes 4 consecutive cols of one row.
template <int N, int K, int K2, bool BIAS, bool RS>
__global__ __launch_bounds__(256) void gemm_bias2(const float* __restrict__ A,
                                                  const float* __restrict__ W,
                                                  const float* __restrict__ bias,
                                                  const float* __restrict__ A2,
                                                  const float* __restrict__ W2,
                                                  const float* __restrict__ rs,
                                                  float* __restrict__ out, int M) {
    constexpr int CG = N / 4;        // col groups per row
    constexpr int ROWS = 256 / CG;   // rows per block
    int tid = threadIdx.x;
    int cg = tid % CG;
    int rl = tid / CG;
    int row = blockIdx.x * ROWS + rl;
    if (row >= M) return;
    int col = cg * 4;

    float4 acc;
    if (BIAS) {
        acc = *(const float4*)(bias + col);
    } else {
        acc.x = acc.y = acc.z = acc.w = 0.0f;
    }

    const float* a = A + (size_t)row * K;
#pragma unroll 4
    for (int k = 0; k < K; ++k) {
        float av = a[k];
        float4 w = *(const float4*)(W + (size_t)k * N + col);
        acc.x += av * w.x;
        acc.y += av * w.y;
        acc.z += av * w.z;
        acc.w += av * w.w;
    }
    if constexpr (K2 > 0) {
        const float* a2 = A2 + (size_t)row * K2;
#pragma unroll 4
        for (int k = 0; k < K2; ++k) {
            float av = a2[k];
            float4 w = *(const float4*)(W2 + (size_t)k * N + col);
            acc.x += av * w.x;
            acc.y += av * w.y;
            acc.z += av * w.z;
            acc.w += av * w.w;
        }
    }
    if constexpr (RS) {
        float sc = rs[row];
        acc.x *= sc; acc.y *= sc; acc.z *= sc; acc.w *= sc;
    }
    *(float4*)(out + (size_t)row * N + col) = acc;
}

// ---------------------------------------------------------------------------
// Fused GCN gather: out[r] = dinv[r] * (sum_{s in N(r)} h[s] + h[r]) + bias
// (h is pre-scaled per-row by dinv at GEMM time). One 64-lane wave per row;
// lane owns 2 consecutive floats of the 128-wide row.
__global__ __launch_bounds__(256) void gcn_gather(const float* __restrict__ h,
                                                  const int* __restrict__ rowptr,
                                                  const int* __restrict__ col,
                                                  const float* __restrict__ dinv,
                                                  const float* __restrict__ bias,
                                                  float* __restrict__ out, int n) {
    int wid = threadIdx.x >> 6;
    int lane = threadIdx.x & 63;
    int r = blockIdx.x * 4 + wid;
    if (r >= n) return;
    const float2* hp = (const float2*)h;
    float2 acc = hp[(size_t)r * 64 + lane];          // self-loop term (pre-scaled)
    int e = rowptr[r], end = rowptr[r + 1];
    for (; e + 3 < end; e += 4) {
        int s0 = col[e], s1 = col[e + 1], s2 = col[e + 2], s3 = col[e + 3];
        float2 v0 = hp[(size_t)s0 * 64 + lane];
        float2 v1 = hp[(size_t)s1 * 64 + lane];
        float2 v2 = hp[(size_t)s2 * 64 + lane];
        float2 v3 = hp[(size_t)s3 * 64 + lane];
        acc.x += (v0.x + v1.x) + (v2.x + v3.x);
        acc.y += (v0.y + v1.y) + (v2.y + v3.y);
    }
    for (; e < end; ++e) {
        int s = col[e];
        float2 v = hp[(size_t)s * 64 + lane];
        acc.x += v.x; acc.y += v.y;
    }
    float dv = dinv[r];
    float2 b = ((const float2*)bias)[lane];
    acc.x = acc.x * dv + b.x;
    acc.y = acc.y * dv + b.y;
    ((float2*)out)[(size_t)r * 64 + lane] = acc;
}

// SAGE mean gather: out[r] = (sum_{s in N(r)} x[s]) * invcnt[r]   (dim = 128)
__global__ __launch_bounds__(256) void sage_gather(const float* __restrict__ x,
                                                   const int* __restrict__ rowptr,
                                                   const int* __restrict__ col,
                                                   const float* __restrict__ invcnt,
                                                   float* __restrict__ out, int n) {
    int wid = threadIdx.x >> 6;
    int lane = threadIdx.x & 63;
    int r = blockIdx.x * 4 + wid;
    if (r >= n) return;
    const float2* xp = (const float2*)x;
    float2 acc; acc.x = 0.0f; acc.y = 0.0f;
    int e = rowptr[r], end = rowptr[r + 1];
    for (; e + 3 < end; e += 4) {
        int s0 = col[e], s1 = col[e + 1], s2 = col[e + 2], s3 = col[e + 3];
        float2 v0 = xp[(size_t)s0 * 64 + lane];
        float2 v1 = xp[(size_t)s1 * 64 + lane];
        float2 v2 = xp[(size_t)s2 * 64 + lane];
        float2 v3 = xp[(size_t)s3 * 64 + lane];
        acc.x += (v0.x + v1.x) + (v2.x + v3.x);
        acc.y += (v0.y + v1.y) + (v2.y + v3.y);
    }
    for (; e < end; ++e) {
        int s = col[e];
        float2 v = xp[(size_t)s * 64 + lane];
        acc.x += v.x; acc.y += v.y;
    }
    float ic = invcnt[r];
    acc.x *= ic; acc.y *= ic;
    ((float2*)out)[(size_t)r * 64 + lane] = acc;
}

// ---------------------------------------------------------------------------
extern "C" void kernel_launch(void* const* d_in, const int* in_sizes, int n_in,
                              void* d_out, int out_size, void* d_ws, size_t ws_size,
                              hipStream_t stream) {
    const float* x_region = (const float*)d_in[0];   // [NR,128]
    const float* x_subject = (const float*)d_in[1];  // [NS,64]
    const int* rr_src = (const int*)d_in[2];
    const int* rr_dst = (const int*)d_in[3];
    const int* hs_src = (const int*)d_in[4];
    const int* hs_dst = (const int*)d_in[5];
    const float* Wg1 = (const float*)d_in[6];
    const float* bg1 = (const float*)d_in[7];
    const float* Wl1 = (const float*)d_in[8];
    const float* bl1 = (const float*)d_in[9];
    const float* Wr1 = (const float*)d_in[10];  // [64,128]
    const float* Wg2 = (const float*)d_in[11];
    const float* bg2 = (const float*)d_in[12];
    const float* Wl2 = (const float*)d_in[13];
    const float* bl2 = (const float*)d_in[14];
    const float* Wr2 = (const float*)d_in[15];  // [128,128]
    const float* Wout = (const float*)d_in[16]; // [128,64]
    const float* bout = (const float*)d_in[17]; // [64]
    float* out = (float*)d_out;

    // workspace layout
    float* ws = (float*)d_ws;
    float* A  = ws;                        // NR*128  (h1', later h2')
    float* C  = A + (size_t)NR * 128;      // NR*128  (r1, later r2)
    float* SA = C + (size_t)NR * 128;      // NS*128  (sage mean)
    float* SB = SA + (size_t)NS * 128;     // NS*128  (s1)
    float* SC = SB + (size_t)NS * 128;     // NS*128  (s2)
    float* dinv   = SC + (size_t)NS * 128; // NR
    float* invcnt = dinv + NR;             // NS
    int* rrRowptr = (int*)(invcnt + NS);   // NR+1
    int* rrCursor = rrRowptr + NR + 1;     // NR (counts -> cursor)
    int* rrCol    = rrCursor + NR;         // ERR_E
    int* hsRowptr = rrCol + ERR_E;         // NS+1
    int* hsCursor = hsRowptr + NS + 1;     // NS
    int* hsCol    = hsCursor + NS;         // EHS_E

    const int TB = 256;

    // ---------------- CSR build (shared by both layers) ----------------
    hipMemsetAsync(rrCursor, 0, (size_t)NR * sizeof(int), stream);
    hipMemsetAsync(hsCursor, 0, (size_t)NS * sizeof(int), stream);
    count_edges_i<<<(ERR_E + TB - 1) / TB, TB, 0, stream>>>(rr_dst, rrCursor, ERR_E);
    count_edges_i<<<(EHS_E + TB - 1) / TB, TB, 0, stream>>>(hs_dst, hsCursor, EHS_E);
    scan_build<0><<<1, 1024, 0, stream>>>(rrCursor, rrRowptr, dinv, NR);
    scan_build<1><<<1, 1024, 0, stream>>>(hsCursor, hsRowptr, invcnt, NS);
    fill_csr<<<(ERR_E + TB - 1) / TB, TB, 0, stream>>>(rr_src, rr_dst, rrCursor, rrCol, ERR_E);
    fill_csr<<<(EHS_E + TB - 1) / TB, TB, 0, stream>>>(hs_src, hs_dst, hsCursor, hsCol, EHS_E);

    // ---------------- Layer 1 ----------------
    // h1' = (x_region @ Wg1) * dinv -> A
    gemm_bias2<128, 128, 0, false, true><<<(NR + 7) / 8, TB, 0, stream>>>(
        x_region, Wg1, nullptr, nullptr, nullptr, dinv, A, NR);
    // r1 = dinv*(gather(A)+self) + bg1 -> C
    gcn_gather<<<(NR + 3) / 4, TB, 0, stream>>>(A, rrRowptr, rrCol, dinv, bg1, C, NR);
    // SAGE1 mean of x_region -> SA
    sage_gather<<<(NS + 3) / 4, TB, 0, stream>>>(x_region, hsRowptr, hsCol, invcnt, SA, NS);
    // s1 = SA @ Wl1 + bl1 + x_subject @ Wr1 -> SB
    gemm_bias2<128, 128, 64, true, false><<<(NS + 7) / 8, TB, 0, stream>>>(
        SA, Wl1, bl1, x_subject, Wr1, nullptr, SB, NS);

    // ---------------- Layer 2 ----------------
    // SAGE2 mean of r1 (C) -> SA   (do this before C is overwritten)
    sage_gather<<<(NS + 3) / 4, TB, 0, stream>>>(C, hsRowptr, hsCol, invcnt, SA, NS);
    // s2 = SA @ Wl2 + bl2 + s1 @ Wr2 -> SC
    gemm_bias2<128, 128, 128, true, false><<<(NS + 7) / 8, TB, 0, stream>>>(
        SA, Wl2, bl2, SB, Wr2, nullptr, SC, NS);
    // h2' = (r1 @ Wg2) * dinv -> A
    gemm_bias2<128, 128, 0, false, true><<<(NR + 7) / 8, TB, 0, stream>>>(
        C, Wg2, nullptr, nullptr, nullptr, dinv, A, NR);
    // r2 = dinv*(gather(A)+self) + bg2 -> C (overwrite r1)
    gcn_gather<<<(NR + 3) / 4, TB, 0, stream>>>(A, rrRowptr, rrCol, dinv, bg2, C, NR);

    // ---------------- Output ----------------
    gemm_bias2<64, 128, 0, true, false><<<(NR + 15) / 16, TB, 0, stream>>>(
        C, Wout, bout, nullptr, nullptr, nullptr, out, NR);
    gemm_bias2<64, 128, 0, true, false><<<(NS + 15) / 16, TB, 0, stream>>>(
        SC, Wout, bout, nullptr, nullptr, nullptr, out + (size_t)NR * 64, NS);
}

// Round 6
// 784.060 us; speedup vs baseline: 6.7610x; 1.2256x over previous
//
#include <hip/hip_runtime.h>
#include <hip/hip_bf16.h>
#include <cstddef>

// Problem constants (from reference)
#define NR 50000
#define NS 8192
#define DR 128
#define DSUBJ 64
#define HID 128
#define OUTD 64
#define ERR_E 1000000
#define EHS_E 400000

// ---------------------------------------------------------------------------
// count in-degree (int): cnt[dst[e]] += 1
__global__ __launch_bounds__(256) void count_edges_i(const int* __restrict__ dst,
                                                     int* __restrict__ cnt, int E) {
    int e = blockIdx.x * 256 + threadIdx.x;
    if (e < E) atomicAdd(&cnt[dst[e]], 1);
}

// Single-block scan: rowptr[i+1] = prefix(cnt), cursor[i] = exclusive prefix,
// scale[i] = MODE0: rsqrt(cnt+1) (GCN dinv) / MODE1: 1/max(cnt,1) (SAGE inv-count).
template <int MODE>
__global__ __launch_bounds__(1024) void scan_build(int* __restrict__ cnt_cursor,
                                                   int* __restrict__ rowptr,
                                                   float* __restrict__ scale, int n) {
    __shared__ int s[1024];
    __shared__ int carry;
    int tid = threadIdx.x;
    if (tid == 0) { carry = 0; rowptr[0] = 0; }
    __syncthreads();
    for (int base = 0; base < n; base += 1024) {
        int i = base + tid;
        int v = (i < n) ? cnt_cursor[i] : 0;
        s[tid] = v;
        __syncthreads();
#pragma unroll
        for (int off = 1; off < 1024; off <<= 1) {
            int t = (tid >= off) ? s[tid - off] : 0;
            __syncthreads();
            s[tid] += t;
            __syncthreads();
        }
        int incl = s[tid];
        int c = carry;
        if (i < n) {
            rowptr[i + 1] = c + incl;
            cnt_cursor[i] = c + incl - v;   // exclusive prefix = fill cursor
            if (MODE == 0) scale[i] = rsqrtf((float)(v + 1));
            else           scale[i] = 1.0f / fmaxf((float)v, 1.0f);
        }
        __syncthreads();
        if (tid == 0) carry = c + s[1023];
        __syncthreads();
    }
}

// fill CSR column array: col[cursor[dst[e]]++] = src[e]
__global__ __launch_bounds__(256) void fill_csr(const int* __restrict__ src,
                                                const int* __restrict__ dst,
                                                int* __restrict__ cursor,
                                                int* __restrict__ col, int E) {
    int e = blockIdx.x * 256 + threadIdx.x;
    if (e < E) {
        int p = atomicAdd(&cursor[dst[e]], 1);
        col[p] = src[e];
    }
}

// ---------------------------------------------------------------------------
// LDS-staged GEMM: out[M x N] (=|+=) A[M x K] @ W[K x N] [*rs[row]] [+bias]
// W staged once per block in LDS (K*N*4 <= 64 KB). 64 rows per block,
// 256 threads, each thread computes RPT rows x 4 cols with float4 A loads.
template <int N, int K, bool BIAS, bool RS, bool ACCUM>
__global__ __launch_bounds__(256, 2) void gemm_lds(const float* __restrict__ A,
                                                   const float* __restrict__ W,
                                                   const float* __restrict__ bias,
                                                   const float* __restrict__ rs,
                                                   float* __restrict__ out, int M) {
    constexpr int CG = N / 4;          // col groups (32 for N=128, 16 for N=64)
    constexpr int SLOTS = 256 / CG;    // row slots per block
    constexpr int RPT = 64 / SLOTS;    // rows per thread
    __shared__ float wl[K * N];

    // stage W -> LDS (coalesced float4)
    for (int i = threadIdx.x * 4; i < K * N; i += 1024)
        *(float4*)&wl[i] = *(const float4*)&W[i];
    __syncthreads();

    int cg = threadIdx.x & (CG - 1);
    int rl = threadIdx.x / CG;
    int col = cg * 4;
    int row0 = blockIdx.x * 64 + rl * RPT;

    float4 acc[RPT];
#pragma unroll
    for (int j = 0; j < RPT; ++j) { acc[j].x = acc[j].y = acc[j].z = acc[j].w = 0.0f; }

#pragma unroll 2
    for (int k0 = 0; k0 < K; k0 += 4) {
        float4 a[RPT];
#pragma unroll
        for (int j = 0; j < RPT; ++j) {
            int r = row0 + j; if (r > M - 1) r = M - 1;   // clamp (stores are guarded)
            a[j] = *(const float4*)(A + (size_t)r * K + k0);
        }
#pragma unroll
        for (int kk = 0; kk < 4; ++kk) {
            float4 w = *(float4*)&wl[(k0 + kk) * N + col];
#pragma unroll
            for (int j = 0; j < RPT; ++j) {
                float av = (kk == 0) ? a[j].x : (kk == 1) ? a[j].y : (kk == 2) ? a[j].z : a[j].w;
                acc[j].x += av * w.x;
                acc[j].y += av * w.y;
                acc[j].z += av * w.z;
                acc[j].w += av * w.w;
            }
        }
    }

    float4 b4;
    if (BIAS) b4 = *(const float4*)(bias + col);
#pragma unroll
    for (int j = 0; j < RPT; ++j) {
        int r = row0 + j;
        if (r >= M) continue;
        float4 v = acc[j];
        if (RS) { float sc = rs[r]; v.x *= sc; v.y *= sc; v.z *= sc; v.w *= sc; }
        if (BIAS) { v.x += b4.x; v.y += b4.y; v.z += b4.z; v.w += b4.w; }
        float* op = out + (size_t)r * N + col;
        if (ACCUM) {
            float4 o = *(const float4*)op;
            v.x += o.x; v.y += o.y; v.z += o.z; v.w += o.w;
        }
        *(float4*)op = v;
    }
}

// ---------------------------------------------------------------------------
// Fused GCN gather: out[r] = dinv[r] * (sum_{s in N(r)} h[s] + h[r]) + bias
// (h pre-scaled per-row by dinv). One 64-lane wave per row; lane owns 2 floats.
__global__ __launch_bounds__(256) void gcn_gather(const float* __restrict__ h,
                                                  const int* __restrict__ rowptr,
                                                  const int* __restrict__ col,
                                                  const float* __restrict__ dinv,
                                                  const float* __restrict__ bias,
                                                  float* __restrict__ out, int n) {
    int wid = threadIdx.x >> 6;
    int lane = threadIdx.x & 63;
    int r = blockIdx.x * 4 + wid;
    if (r >= n) return;
    const float2* hp = (const float2*)h;
    float2 acc = hp[(size_t)r * 64 + lane];          // self-loop term (pre-scaled)
    int e = rowptr[r], end = rowptr[r + 1];
    for (; e + 3 < end; e += 4) {
        int s0 = col[e], s1 = col[e + 1], s2 = col[e + 2], s3 = col[e + 3];
        float2 v0 = hp[(size_t)s0 * 64 + lane];
        float2 v1 = hp[(size_t)s1 * 64 + lane];
        float2 v2 = hp[(size_t)s2 * 64 + lane];
        float2 v3 = hp[(size_t)s3 * 64 + lane];
        acc.x += (v0.x + v1.x) + (v2.x + v3.x);
        acc.y += (v0.y + v1.y) + (v2.y + v3.y);
    }
    for (; e < end; ++e) {
        int s = col[e];
        float2 v = hp[(size_t)s * 64 + lane];
        acc.x += v.x; acc.y += v.y;
    }
    float dv = dinv[r];
    float2 b = ((const float2*)bias)[lane];
    acc.x = acc.x * dv + b.x;
    acc.y = acc.y * dv + b.y;
    ((float2*)out)[(size_t)r * 64 + lane] = acc;
}

// SAGE mean gather: out[r] = (sum_{s in N(r)} x[s]) * invcnt[r]   (dim = 128)
__global__ __launch_bounds__(256) void sage_gather(const float* __restrict__ x,
                                                   const int* __restrict__ rowptr,
                                                   const int* __restrict__ col,
                                                   const float* __restrict__ invcnt,
                                                   float* __restrict__ out, int n) {
    int wid = threadIdx.x >> 6;
    int lane = threadIdx.x & 63;
    int r = blockIdx.x * 4 + wid;
    if (r >= n) return;
    const float2* xp = (const float2*)x;
    float2 acc; acc.x = 0.0f; acc.y = 0.0f;
    int e = rowptr[r], end = rowptr[r + 1];
    for (; e + 3 < end; e += 4) {
        int s0 = col[e], s1 = col[e + 1], s2 = col[e + 2], s3 = col[e + 3];
        float2 v0 = xp[(size_t)s0 * 64 + lane];
        float2 v1 = xp[(size_t)s1 * 64 + lane];
        float2 v2 = xp[(size_t)s2 * 64 + lane];
        float2 v3 = xp[(size_t)s3 * 64 + lane];
        acc.x += (v0.x + v1.x) + (v2.x + v3.x);
        acc.y += (v0.y + v1.y) + (v2.y + v3.y);
    }
    for (; e < end; ++e) {
        int s = col[e];
        float2 v = xp[(size_t)s * 64 + lane];
        acc.x += v.x; acc.y += v.y;
    }
    float ic = invcnt[r];
    acc.x *= ic; acc.y *= ic;
    ((float2*)out)[(size_t)r * 64 + lane] = acc;
}

// ---------------------------------------------------------------------------
extern "C" void kernel_launch(void* const* d_in, const int* in_sizes, int n_in,
                              void* d_out, int out_size, void* d_ws, size_t ws_size,
                              hipStream_t stream) {
    const float* x_region = (const float*)d_in[0];   // [NR,128]
    const float* x_subject = (const float*)d_in[1];  // [NS,64]
    const int* rr_src = (const int*)d_in[2];
    const int* rr_dst = (const int*)d_in[3];
    const int* hs_src = (const int*)d_in[4];
    const int* hs_dst = (const int*)d_in[5];
    const float* Wg1 = (const float*)d_in[6];
    const float* bg1 = (const float*)d_in[7];
    const float* Wl1 = (const float*)d_in[8];
    const float* bl1 = (const float*)d_in[9];
    const float* Wr1 = (const float*)d_in[10];  // [64,128]
    const float* Wg2 = (const float*)d_in[11];
    const float* bg2 = (const float*)d_in[12];
    const float* Wl2 = (const float*)d_in[13];
    const float* bl2 = (const float*)d_in[14];
    const float* Wr2 = (const float*)d_in[15];  // [128,128]
    const float* Wout = (const float*)d_in[16]; // [128,64]
    const float* bout = (const float*)d_in[17]; // [64]
    float* out = (float*)d_out;

    // workspace layout
    float* ws = (float*)d_ws;
    float* A  = ws;                        // NR*128  (h1', later h2')
    float* C  = A + (size_t)NR * 128;      // NR*128  (r1, later r2)
    float* SA = C + (size_t)NR * 128;      // NS*128  (sage mean)
    float* SB = SA + (size_t)NS * 128;     // NS*128  (s1)
    float* SC = SB + (size_t)NS * 128;     // NS*128  (s2)
    float* dinv   = SC + (size_t)NS * 128; // NR
    float* invcnt = dinv + NR;             // NS
    int* rrRowptr = (int*)(invcnt + NS);   // NR+1
    int* rrCursor = rrRowptr + NR + 1;     // NR (counts -> cursor)
    int* rrCol    = rrCursor + NR;         // ERR_E
    int* hsRowptr = rrCol + ERR_E;         // NS+1
    int* hsCursor = hsRowptr + NS + 1;     // NS
    int* hsCol    = hsCursor + NS;         // EHS_E

    const int TB = 256;

    // ---------------- CSR build (shared by both layers) ----------------
    hipMemsetAsync(rrCursor, 0, (size_t)NR * sizeof(int), stream);
    hipMemsetAsync(hsCursor, 0, (size_t)NS * sizeof(int), stream);
    count_edges_i<<<(ERR_E + TB - 1) / TB, TB, 0, stream>>>(rr_dst, rrCursor, ERR_E);
    count_edges_i<<<(EHS_E + TB - 1) / TB, TB, 0, stream>>>(hs_dst, hsCursor, EHS_E);
    scan_build<0><<<1, 1024, 0, stream>>>(rrCursor, rrRowptr, dinv, NR);
    scan_build<1><<<1, 1024, 0, stream>>>(hsCursor, hsRowptr, invcnt, NS);
    fill_csr<<<(ERR_E + TB - 1) / TB, TB, 0, stream>>>(rr_src, rr_dst, rrCursor, rrCol, ERR_E);
    fill_csr<<<(EHS_E + TB - 1) / TB, TB, 0, stream>>>(hs_src, hs_dst, hsCursor, hsCol, EHS_E);

    // ---------------- Layer 1 ----------------
    // h1' = (x_region @ Wg1) * dinv -> A
    gemm_lds<128, 128, false, true, false><<<(NR + 63) / 64, TB, 0, stream>>>(
        x_region, Wg1, nullptr, dinv, A, NR);
    // r1 = dinv*(gather(A)+self) + bg1 -> C
    gcn_gather<<<(NR + 3) / 4, TB, 0, stream>>>(A, rrRowptr, rrCol, dinv, bg1, C, NR);
    // SAGE1 mean of x_region -> SA
    sage_gather<<<(NS + 3) / 4, TB, 0, stream>>>(x_region, hsRowptr, hsCol, invcnt, SA, NS);
    // s1 = SA @ Wl1 + bl1 -> SB ; then SB += x_subject @ Wr1
    gemm_lds<128, 128, true, false, false><<<(NS + 63) / 64, TB, 0, stream>>>(
        SA, Wl1, bl1, nullptr, SB, NS);
    gemm_lds<128, 64, false, false, true><<<(NS + 63) / 64, TB, 0, stream>>>(
        x_subject, Wr1, nullptr, nullptr, SB, NS);

    // ---------------- Layer 2 ----------------
    // SAGE2 mean of r1 (C) -> SA   (before C is overwritten)
    sage_gather<<<(NS + 3) / 4, TB, 0, stream>>>(C, hsRowptr, hsCol, invcnt, SA, NS);
    // s2 = SA @ Wl2 + bl2 -> SC ; then SC += SB @ Wr2
    gemm_lds<128, 128, true, false, false><<<(NS + 63) / 64, TB, 0, stream>>>(
        SA, Wl2, bl2, nullptr, SC, NS);
    gemm_lds<128, 128, false, false, true><<<(NS + 63) / 64, TB, 0, stream>>>(
        SB, Wr2, nullptr, nullptr, SC, NS);
    // h2' = (r1 @ Wg2) * dinv -> A
    gemm_lds<128, 128, false, true, false><<<(NR + 63) / 64, TB, 0, stream>>>(
        C, Wg2, nullptr, dinv, A, NR);
    // r2 = dinv*(gather(A)+self) + bg2 -> C
    gcn_gather<<<(NR + 3) / 4, TB, 0, stream>>>(A, rrRowptr, rrCol, dinv, bg2, C, NR);

    // ---------------- Output ----------------
    gemm_lds<64, 128, true, false, false><<<(NR + 63) / 64, TB, 0, stream>>>(
        C, Wout, bout, nullptr, out, NR);
    gemm_lds<64, 128, true, false, false><<<(NS + 63) / 64, TB, 0, stream>>>(
        SC, Wout, bout, nullptr, out + (size_t)NR * 64, NS);
}

// Round 10
// 689.097 us; speedup vs baseline: 7.6927x; 1.1378x over previous
//
#include <hip/hip_runtime.h>
#include <hip/hip_bf16.h>
#include <cstddef>

// Problem constants (from reference)
#define NR 50000
#define NS 8192
#define DR 128
#define DSUBJ 64
#define HID 128
#define OUTD 64
#define ERR_E 1000000
#define EHS_E 400000

// ---------------------------------------------------------------------------
// wave-level inclusive scan (64 lanes)
__device__ inline int wave_incl_scan(int x, int lane) {
#pragma unroll
    for (int off = 1; off < 64; off <<= 1) {
        int t = __shfl_up(x, off, 64);
        if (lane >= off) x += t;
    }
    return x;
}

// count in-degree for both graphs in one launch
__global__ __launch_bounds__(256) void count_edges_both(const int* __restrict__ rr_dst,
                                                        const int* __restrict__ hs_dst,
                                                        int* __restrict__ rrCnt,
                                                        int* __restrict__ hsCnt) {
    int t = blockIdx.x * 256 + threadIdx.x;
    if (t < ERR_E) {
        atomicAdd(&rrCnt[rr_dst[t]], 1);
    } else {
        int u = t - ERR_E;
        if (u < EHS_E) atomicAdd(&hsCnt[hs_dst[u]], 1);
    }
}

// phase 1: per-block (1024-elem chunk) sums
__global__ __launch_bounds__(1024) void block_sums(const int* __restrict__ cnt,
                                                   int* __restrict__ partial, int n) {
    int tid = threadIdx.x, lane = tid & 63, wid = tid >> 6;
    int i = blockIdx.x * 1024 + tid;
    int v = (i < n) ? cnt[i] : 0;
    int s = v;
#pragma unroll
    for (int off = 1; off < 64; off <<= 1) s += __shfl_xor(s, off, 64);
    __shared__ int wsum[16];
    if (lane == 0) wsum[wid] = s;
    __syncthreads();
    if (tid == 0) {
        int tot = 0;
#pragma unroll
        for (int w = 0; w < 16; ++w) tot += wsum[w];
        partial[blockIdx.x] = tot;
    }
}

// phase 2: exclusive-scan the partials in place (nb <= 64), one wave
__global__ __launch_bounds__(64) void scan_partials(int* __restrict__ partial, int nb) {
    int lane = threadIdx.x;
    int v = (lane < nb) ? partial[lane] : 0;
    int incl = wave_incl_scan(v, lane);
    if (lane < nb) partial[lane] = incl - v;
}

// phase 3: block scan + partial offset; write rowptr[i+1], cursor (in place), scale
template <int MODE>
__global__ __launch_bounds__(1024) void scan_finalize(int* __restrict__ cnt_cursor,
                                                      const int* __restrict__ partial,
                                                      int* __restrict__ rowptr,
                                                      float* __restrict__ scale, int n) {
    int tid = threadIdx.x, lane = tid & 63, wid = tid >> 6;
    int i = blockIdx.x * 1024 + tid;
    int v = (i < n) ? cnt_cursor[i] : 0;
    int incl = wave_incl_scan(v, lane);
    __shared__ int wsum[16];
    if (lane == 63) wsum[wid] = incl;
    __syncthreads();
    if (wid == 0 && lane < 16) {
        int orig = wsum[lane];
        int wv = orig;
#pragma unroll
        for (int off = 1; off < 16; off <<= 1) {
            int t = __shfl_up(wv, off, 64);
            if (lane >= off) wv += t;
        }
        wsum[lane] = wv - orig;   // exclusive within block
    }
    __syncthreads();
    int excl = partial[blockIdx.x] + wsum[wid] + incl - v;
    if (i < n) {
        rowptr[i + 1] = excl + v;
        cnt_cursor[i] = excl;     // fill cursor
        if (MODE == 0) scale[i] = rsqrtf((float)(v + 1));
        else           scale[i] = 1.0f / fmaxf((float)v, 1.0f);
    }
    if (i == 0) rowptr[0] = 0;
}

// fill CSR column arrays for both graphs in one launch
__global__ __launch_bounds__(256) void fill_csr_both(const int* __restrict__ rr_src,
                                                     const int* __restrict__ rr_dst,
                                                     int* __restrict__ rrCursor,
                                                     int* __restrict__ rrCol,
                                                     const int* __restrict__ hs_src,
                                                     const int* __restrict__ hs_dst,
                                                     int* __restrict__ hsCursor,
                                                     int* __restrict__ hsCol) {
    int t = blockIdx.x * 256 + threadIdx.x;
    if (t < ERR_E) {
        int p = atomicAdd(&rrCursor[rr_dst[t]], 1);
        rrCol[p] = rr_src[t];
    } else {
        int u = t - ERR_E;
        if (u < EHS_E) {
            int p = atomicAdd(&hsCursor[hs_dst[u]], 1);
            hsCol[p] = hs_src[u];
        }
    }
}

// ---------------------------------------------------------------------------
// LDS-staged GEMM: out[M x N] (=|+=) A[M x K] @ W[K x N] [*rs[row]] [+bias]
// W staged once per block in LDS (K*N*4 <= 64 KB). 64 rows per block,
// 256 threads, each thread computes RPT rows x 4 cols with float4 A loads.
template <int N, int K, bool BIAS, bool RS, bool ACCUM>
__global__ __launch_bounds__(256, 2) void gemm_lds(const float* __restrict__ A,
                                                   const float* __restrict__ W,
                                                   const float* __restrict__ bias,
                                                   const float* __restrict__ rs,
                                                   float* __restrict__ out, int M) {
    constexpr int CG = N / 4;          // col groups (32 for N=128, 16 for N=64)
    constexpr int SLOTS = 256 / CG;    // row slots per block
    constexpr int RPT = 64 / SLOTS;    // rows per thread
    __shared__ float wl[K * N];

    // stage W -> LDS (coalesced float4)
    for (int i = threadIdx.x * 4; i < K * N; i += 1024)
        *(float4*)&wl[i] = *(const float4*)&W[i];
    __syncthreads();

    int cg = threadIdx.x & (CG - 1);
    int rl = threadIdx.x / CG;
    int col = cg * 4;
    int row0 = blockIdx.x * 64 + rl * RPT;

    float4 acc[RPT];
#pragma unroll
    for (int j = 0; j < RPT; ++j) { acc[j].x = acc[j].y = acc[j].z = acc[j].w = 0.0f; }

#pragma unroll 2
    for (int k0 = 0; k0 < K; k0 += 4) {
        float4 a[RPT];
#pragma unroll
        for (int j = 0; j < RPT; ++j) {
            int r = row0 + j; if (r > M - 1) r = M - 1;   // clamp (stores are guarded)
            a[j] = *(const float4*)(A + (size_t)r * K + k0);
        }
#pragma unroll
        for (int kk = 0; kk < 4; ++kk) {
            float4 w = *(float4*)&wl[(k0 + kk) * N + col];
#pragma unroll
            for (int j = 0; j < RPT; ++j) {
                float av = (kk == 0) ? a[j].x : (kk == 1) ? a[j].y : (kk == 2) ? a[j].z : a[j].w;
                acc[j].x += av * w.x;
                acc[j].y += av * w.y;
                acc[j].z += av * w.z;
                acc[j].w += av * w.w;
            }
        }
    }

    float4 b4;
    if (BIAS) b4 = *(const float4*)(bias + col);
#pragma unroll
    for (int j = 0; j < RPT; ++j) {
        int r = row0 + j;
        if (r >= M) continue;
        float4 v = acc[j];
        if (RS) { float sc = rs[r]; v.x *= sc; v.y *= sc; v.z *= sc; v.w *= sc; }
        if (BIAS) { v.x += b4.x; v.y += b4.y; v.z += b4.z; v.w += b4.w; }
        float* op = out + (size_t)r * N + col;
        if (ACCUM) {
            float4 o = *(const float4*)op;
            v.x += o.x; v.y += o.y; v.z += o.z; v.w += o.w;
        }
        *(float4*)op = v;
    }
}

// ---------------------------------------------------------------------------
// Fused GCN gather: out[r] = dinv[r] * (sum_{s in N(r)} h[s] + h[r]) + bias
// (h pre-scaled per-row by dinv). One 64-lane wave per row; lane owns 2 floats.
__global__ __launch_bounds__(256) void gcn_gather(const float* __restrict__ h,
                                                  const int* __restrict__ rowptr,
                                                  const int* __restrict__ col,
                                                  const float* __restrict__ dinv,
                                                  const float* __restrict__ bias,
                                                  float* __restrict__ out, int n) {
    int wid = threadIdx.x >> 6;
    int lane = threadIdx.x & 63;
    int r = blockIdx.x * 4 + wid;
    if (r >= n) return;
    const float2* hp = (const float2*)h;
    float2 acc = hp[(size_t)r * 64 + lane];          // self-loop term (pre-scaled)
    int e = rowptr[r], end = rowptr[r + 1];
    for (; e + 7 < end; e += 8) {
        int s0 = col[e],     s1 = col[e + 1], s2 = col[e + 2], s3 = col[e + 3];
        int s4 = col[e + 4], s5 = col[e + 5], s6 = col[e + 6], s7 = col[e + 7];
        float2 v0 = hp[(size_t)s0 * 64 + lane];
        float2 v1 = hp[(size_t)s1 * 64 + lane];
        float2 v2 = hp[(size_t)s2 * 64 + lane];
        float2 v3 = hp[(size_t)s3 * 64 + lane];
        float2 v4 = hp[(size_t)s4 * 64 + lane];
        float2 v5 = hp[(size_t)s5 * 64 + lane];
        float2 v6 = hp[(size_t)s6 * 64 + lane];
        float2 v7 = hp[(size_t)s7 * 64 + lane];
        acc.x += ((v0.x + v1.x) + (v2.x + v3.x)) + ((v4.x + v5.x) + (v6.x + v7.x));
        acc.y += ((v0.y + v1.y) + (v2.y + v3.y)) + ((v4.y + v5.y) + (v6.y + v7.y));
    }
    for (; e + 3 < end; e += 4) {
        int s0 = col[e], s1 = col[e + 1], s2 = col[e + 2], s3 = col[e + 3];
        float2 v0 = hp[(size_t)s0 * 64 + lane];
        float2 v1 = hp[(size_t)s1 * 64 + lane];
        float2 v2 = hp[(size_t)s2 * 64 + lane];
        float2 v3 = hp[(size_t)s3 * 64 + lane];
        acc.x += (v0.x + v1.x) + (v2.x + v3.x);
        acc.y += (v0.y + v1.y) + (v2.y + v3.y);
    }
    for (; e < end; ++e) {
        int s = col[e];
        float2 v = hp[(size_t)s * 64 + lane];
        acc.x += v.x; acc.y += v.y;
    }
    float dv = dinv[r];
    float2 b = ((const float2*)bias)[lane];
    acc.x = acc.x * dv + b.x;
    acc.y = acc.y * dv + b.y;
    ((float2*)out)[(size_t)r * 64 + lane] = acc;
}

// SAGE mean gather: out[r] = (sum_{s in N(r)} x[s]) * invcnt[r]   (dim = 128)
__global__ __launch_bounds__(256) void sage_gather(const float* __restrict__ x,
                                                   const int* __restrict__ rowptr,
                                                   const int* __restrict__ col,
                                                   const float* __restrict__ invcnt,
                                                   float* __restrict__ out, int n) {
    int wid = threadIdx.x >> 6;
    int lane = threadIdx.x & 63;
    int r = blockIdx.x * 4 + wid;
    if (r >= n) return;
    const float2* xp = (const float2*)x;
    float2 acc; acc.x = 0.0f; acc.y = 0.0f;
    int e = rowptr[r], end = rowptr[r + 1];
    for (; e + 7 < end; e += 8) {
        int s0 = col[e],     s1 = col[e + 1], s2 = col[e + 2], s3 = col[e + 3];
        int s4 = col[e + 4], s5 = col[e + 5], s6 = col[e + 6], s7 = col[e + 7];
        float2 v0 = xp[(size_t)s0 * 64 + lane];
        float2 v1 = xp[(size_t)s1 * 64 + lane];
        float2 v2 = xp[(size_t)s2 * 64 + lane];
        float2 v3 = xp[(size_t)s3 * 64 + lane];
        float2 v4 = xp[(size_t)s4 * 64 + lane];
        float2 v5 = xp[(size_t)s5 * 64 + lane];
        float2 v6 = xp[(size_t)s6 * 64 + lane];
        float2 v7 = xp[(size_t)s7 * 64 + lane];
        acc.x += ((v0.x + v1.x) + (v2.x + v3.x)) + ((v4.x + v5.x) + (v6.x + v7.x));
        acc.y += ((v0.y + v1.y) + (v2.y + v3.y)) + ((v4.y + v5.y) + (v6.y + v7.y));
    }
    for (; e + 3 < end; e += 4) {
        int s0 = col[e], s1 = col[e + 1], s2 = col[e + 2], s3 = col[e + 3];
        float2 v0 = xp[(size_t)s0 * 64 + lane];
        float2 v1 = xp[(size_t)s1 * 64 + lane];
        float2 v2 = xp[(size_t)s2 * 64 + lane];
        float2 v3 = xp[(size_t)s3 * 64 + lane];
        acc.x += (v0.x + v1.x) + (v2.x + v3.x);
        acc.y += (v0.y + v1.y) + (v2.y + v3.y);
    }
    for (; e < end; ++e) {
        int s = col[e];
        float2 v = xp[(size_t)s * 64 + lane];
        acc.x += v.x; acc.y += v.y;
    }
    float ic = invcnt[r];
    acc.x *= ic; acc.y *= ic;
    ((float2*)out)[(size_t)r * 64 + lane] = acc;
}

// ---------------------------------------------------------------------------
extern "C" void kernel_launch(void* const* d_in, const int* in_sizes, int n_in,
                              void* d_out, int out_size, void* d_ws, size_t ws_size,
                              hipStream_t stream) {
    const float* x_region = (const float*)d_in[0];   // [NR,128]
    const float* x_subject = (const float*)d_in[1];  // [NS,64]
    const int* rr_src = (const int*)d_in[2];
    const int* rr_dst = (const int*)d_in[3];
    const int* hs_src = (const int*)d_in[4];
    const int* hs_dst = (const int*)d_in[5];
    const float* Wg1 = (const float*)d_in[6];
    const float* bg1 = (const float*)d_in[7];
    const float* Wl1 = (const float*)d_in[8];
    const float* bl1 = (const float*)d_in[9];
    const float* Wr1 = (const float*)d_in[10];  // [64,128]
    const float* Wg2 = (const float*)d_in[11];
    const float* bg2 = (const float*)d_in[12];
    const float* Wl2 = (const float*)d_in[13];
    const float* bl2 = (const float*)d_in[14];
    const float* Wr2 = (const float*)d_in[15];  // [128,128]
    const float* Wout = (const float*)d_in[16]; // [128,64]
    const float* bout = (const float*)d_in[17]; // [64]
    float* out = (float*)d_out;

    // workspace layout
    float* ws = (float*)d_ws;
    float* A  = ws;                        // NR*128  (h1', later h2')
    float* C  = A + (size_t)NR * 128;      // NR*128  (r1, later r2)
    float* SA = C + (size_t)NR * 128;      // NS*128  (sage mean)
    float* SB = SA + (size_t)NS * 128;     // NS*128  (s1)
    float* SC = SB + (size_t)NS * 128;     // NS*128  (s2)
    float* dinv   = SC + (size_t)NS * 128; // NR
    float* invcnt = dinv + NR;             // NS
    int* rrRowptr = (int*)(invcnt + NS);   // NR+1
    int* rrCursor = rrRowptr + NR + 1;     // NR (counts -> cursor)
    int* rrCol    = rrCursor + NR;         // ERR_E
    int* hsRowptr = rrCol + ERR_E;         // NS+1
    int* hsCursor = hsRowptr + NS + 1;     // NS
    int* hsCol    = hsCursor + NS;         // EHS_E
    int* rrPart   = hsCol + EHS_E;         // 49 partials
    int* hsPart   = rrPart + 64;           // 8 partials

    const int TB = 256;
    constexpr int RR_BLKS = (NR + 1023) / 1024;   // 49
    constexpr int HS_BLKS = (NS + 1023) / 1024;   // 8

    // ---------------- CSR build (shared by both layers) ----------------
    hipMemsetAsync(rrCursor, 0, (size_t)NR * sizeof(int), stream);
    hipMemsetAsync(hsCursor, 0, (size_t)NS * sizeof(int), stream);
    count_edges_both<<<(ERR_E + EHS_E + TB - 1) / TB, TB, 0, stream>>>(
        rr_dst, hs_dst, rrCursor, hsCursor);
    block_sums<<<RR_BLKS, 1024, 0, stream>>>(rrCursor, rrPart, NR);
    block_sums<<<HS_BLKS, 1024, 0, stream>>>(hsCursor, hsPart, NS);
    scan_partials<<<1, 64, 0, stream>>>(rrPart, RR_BLKS);
    scan_partials<<<1, 64, 0, stream>>>(hsPart, HS_BLKS);
    scan_finalize<0><<<RR_BLKS, 1024, 0, stream>>>(rrCursor, rrPart, rrRowptr, dinv, NR);
    scan_finalize<1><<<HS_BLKS, 1024, 0, stream>>>(hsCursor, hsPart, hsRowptr, invcnt, NS);
    fill_csr_both<<<(ERR_E + EHS_E + TB - 1) / TB, TB, 0, stream>>>(
        rr_src, rr_dst, rrCursor, rrCol, hs_src, hs_dst, hsCursor, hsCol);

    // ---------------- Layer 1 ----------------
    // h1' = (x_region @ Wg1) * dinv -> A
    gemm_lds<128, 128, false, true, false><<<(NR + 63) / 64, TB, 0, stream>>>(
        x_region, Wg1, nullptr, dinv, A, NR);
    // r1 = dinv*(gather(A)+self) + bg1 -> C
    gcn_gather<<<(NR + 3) / 4, TB, 0, stream>>>(A, rrRowptr, rrCol, dinv, bg1, C, NR);
    // SAGE1 mean of x_region -> SA
    sage_gather<<<(NS + 3) / 4, TB, 0, stream>>>(x_region, hsRowptr, hsCol, invcnt, SA, NS);
    // s1 = SA @ Wl1 + bl1 -> SB ; then SB += x_subject @ Wr1
    gemm_lds<128, 128, true, false, false><<<(NS + 63) / 64, TB, 0, stream>>>(
        SA, Wl1, bl1, nullptr, SB, NS);
    gemm_lds<128, 64, false, false, true><<<(NS + 63) / 64, TB, 0, stream>>>(
        x_subject, Wr1, nullptr, nullptr, SB, NS);

    // ---------------- Layer 2 ----------------
    // SAGE2 mean of r1 (C) -> SA   (before C is overwritten)
    sage_gather<<<(NS + 3) / 4, TB, 0, stream>>>(C, hsRowptr, hsCol, invcnt, SA, NS);
    // s2 = SA @ Wl2 + bl2 -> SC ; then SC += SB @ Wr2
    gemm_lds<128, 128, true, false, false><<<(NS + 63) / 64, TB, 0, stream>>>(
        SA, Wl2, bl2, nullptr, SC, NS);
    gemm_lds<128, 128, false, false, true><<<(NS + 63) / 64, TB, 0, stream>>>(
        SB, Wr2, nullptr, nullptr, SC, NS);
    // h2' = (r1 @ Wg2) * dinv -> A
    gemm_lds<128, 128, false, true, false><<<(NR + 63) / 64, TB, 0, stream>>>(
        C, Wg2, nullptr, dinv, A, NR);
    // r2 = dinv*(gather(A)+self) + bg2 -> C
    gcn_gather<<<(NR + 3) / 4, TB, 0, stream>>>(A, rrRowptr, rrCol, dinv, bg2, C, NR);

    // ---------------- Output ----------------
    gemm_lds<64, 128, true, false, false><<<(NR + 63) / 64, TB, 0, stream>>>(
        C, Wout, bout, nullptr, out, NR);
    gemm_lds<64, 128, true, false, false><<<(NS + 63) / 64, TB, 0, stream>>>(
        SC, Wout, bout, nullptr, out + (size_t)NR * 64, NS);
}

// Round 17
// 618.110 us; speedup vs baseline: 8.5762x; 1.1148x over previous
//
#include <hip/hip_runtime.h>
#include <hip/hip_bf16.h>
#include <cstddef>

// Problem constants (from reference)
#define NR 50000
#define NS 8192
#define DR 128
#define DSUBJ 64
#define HID 128
#define OUTD 64
#define ERR_E 1000000
#define EHS_E 400000

typedef unsigned int uint32;
typedef unsigned short ushort16;

// bf16 helpers: pair packed in a uint (lo = even col, hi = odd col)
__device__ inline float bf16lo(uint32 u) { return __uint_as_float(u << 16); }
__device__ inline float bf16hi(uint32 u) { return __uint_as_float(u & 0xffff0000u); }
__device__ inline ushort16 f2bf(float f) {            // RNE round
    uint32 u = __float_as_uint(f);
    u += 0x7fffu + ((u >> 16) & 1u);
    return (ushort16)(u >> 16);
}
__device__ inline uint32 pack2bf(float x, float y) {  // RNE round both
    uint32 ux = __float_as_uint(x); ux += 0x7fffu + ((ux >> 16) & 1u);
    uint32 uy = __float_as_uint(y); uy += 0x7fffu + ((uy >> 16) & 1u);
    return (ux >> 16) | (uy & 0xffff0000u);
}

// ---------------------------------------------------------------------------
// wave-level inclusive scan (64 lanes)
__device__ inline int wave_incl_scan(int x, int lane) {
#pragma unroll
    for (int off = 1; off < 64; off <<= 1) {
        int t = __shfl_up(x, off, 64);
        if (lane >= off) x += t;
    }
    return x;
}

// count in-degree for both graphs in one launch
__global__ __launch_bounds__(256) void count_edges_both(const int* __restrict__ rr_dst,
                                                        const int* __restrict__ hs_dst,
                                                        int* __restrict__ rrCnt,
                                                        int* __restrict__ hsCnt) {
    int t = blockIdx.x * 256 + threadIdx.x;
    if (t < ERR_E) {
        atomicAdd(&rrCnt[rr_dst[t]], 1);
    } else {
        int u = t - ERR_E;
        if (u < EHS_E) atomicAdd(&hsCnt[hs_dst[u]], 1);
    }
}

// phase 1: per-block (1024-elem chunk) sums
__global__ __launch_bounds__(1024) void block_sums(const int* __restrict__ cnt,
                                                   int* __restrict__ partial, int n) {
    int tid = threadIdx.x, lane = tid & 63, wid = tid >> 6;
    int i = blockIdx.x * 1024 + tid;
    int v = (i < n) ? cnt[i] : 0;
    int s = v;
#pragma unroll
    for (int off = 1; off < 64; off <<= 1) s += __shfl_xor(s, off, 64);
    __shared__ int wsum[16];
    if (lane == 0) wsum[wid] = s;
    __syncthreads();
    if (tid == 0) {
        int tot = 0;
#pragma unroll
        for (int w = 0; w < 16; ++w) tot += wsum[w];
        partial[blockIdx.x] = tot;
    }
}

// phase 2: exclusive-scan the partials in place (nb <= 64), one wave
__global__ __launch_bounds__(64) void scan_partials(int* __restrict__ partial, int nb) {
    int lane = threadIdx.x;
    int v = (lane < nb) ? partial[lane] : 0;
    int incl = wave_incl_scan(v, lane);
    if (lane < nb) partial[lane] = incl - v;
}

// phase 3: block scan + partial offset; write rowptr[i+1], cursor (in place), scale
template <int MODE>
__global__ __launch_bounds__(1024) void scan_finalize(int* __restrict__ cnt_cursor,
                                                      const int* __restrict__ partial,
                                                      int* __restrict__ rowptr,
                                                      float* __restrict__ scale, int n) {
    int tid = threadIdx.x, lane = tid & 63, wid = tid >> 6;
    int i = blockIdx.x * 1024 + tid;
    int v = (i < n) ? cnt_cursor[i] : 0;
    int incl = wave_incl_scan(v, lane);
    __shared__ int wsum[16];
    if (lane == 63) wsum[wid] = incl;
    __syncthreads();
    if (wid == 0 && lane < 16) {
        int orig = wsum[lane];
        int wv = orig;
#pragma unroll
        for (int off = 1; off < 16; off <<= 1) {
            int t = __shfl_up(wv, off, 64);
            if (lane >= off) wv += t;
        }
        wsum[lane] = wv - orig;   // exclusive within block
    }
    __syncthreads();
    int excl = partial[blockIdx.x] + wsum[wid] + incl - v;
    if (i < n) {
        rowptr[i + 1] = excl + v;
        cnt_cursor[i] = excl;     // fill cursor
        if (MODE == 0) scale[i] = rsqrtf((float)(v + 1));
        else           scale[i] = 1.0f / fmaxf((float)v, 1.0f);
    }
    if (i == 0) rowptr[0] = 0;
}

// fill CSR column arrays for both graphs in one launch
__global__ __launch_bounds__(256) void fill_csr_both(const int* __restrict__ rr_src,
                                                     const int* __restrict__ rr_dst,
                                                     int* __restrict__ rrCursor,
                                                     int* __restrict__ rrCol,
                                                     const int* __restrict__ hs_src,
                                                     const int* __restrict__ hs_dst,
                                                     int* __restrict__ hsCursor,
                                                     int* __restrict__ hsCol) {
    int t = blockIdx.x * 256 + threadIdx.x;
    if (t < ERR_E) {
        int p = atomicAdd(&rrCursor[rr_dst[t]], 1);
        rrCol[p] = rr_src[t];
    } else {
        int u = t - ERR_E;
        if (u < EHS_E) {
            int p = atomicAdd(&hsCursor[hs_dst[u]], 1);
            hsCol[p] = hs_src[u];
        }
    }
}

// cast fp32 -> bf16 (vectorized: 4 floats -> 4 bf16 per thread)
__global__ __launch_bounds__(256) void cast_bf(const float4* __restrict__ in,
                                               ushort16* __restrict__ out, int n4) {
    int i = blockIdx.x * 256 + threadIdx.x;
    if (i < n4) {
        float4 v = in[i];
        ushort16* o = out + (size_t)i * 4;
        o[0] = f2bf(v.x); o[1] = f2bf(v.y); o[2] = f2bf(v.z); o[3] = f2bf(v.w);
    }
}

// ---------------------------------------------------------------------------
// LDS-staged GEMM: out[M x N] (=|+=) A[M x K] @ W[K x N] [*rs[row]] [+bias]
// W staged once per block in LDS. OB: store bf16 instead of fp32.
template <int N, int K, bool BIAS, bool RS, bool ACCUM, bool OB>
__global__ __launch_bounds__(256, 2) void gemm_lds(const float* __restrict__ A,
                                                   const float* __restrict__ W,
                                                   const float* __restrict__ bias,
                                                   const float* __restrict__ rs,
                                                   float* __restrict__ out, int M) {
    constexpr int CG = N / 4;          // col groups (32 for N=128, 16 for N=64)
    constexpr int SLOTS = 256 / CG;    // row slots per block
    constexpr int RPT = 64 / SLOTS;    // rows per thread
    __shared__ float wl[K * N];

    for (int i = threadIdx.x * 4; i < K * N; i += 1024)
        *(float4*)&wl[i] = *(const float4*)&W[i];
    __syncthreads();

    int cg = threadIdx.x & (CG - 1);
    int rl = threadIdx.x / CG;
    int col = cg * 4;
    int row0 = blockIdx.x * 64 + rl * RPT;

    float4 acc[RPT];
#pragma unroll
    for (int j = 0; j < RPT; ++j) { acc[j].x = acc[j].y = acc[j].z = acc[j].w = 0.0f; }

#pragma unroll 2
    for (int k0 = 0; k0 < K; k0 += 4) {
        float4 a[RPT];
#pragma unroll
        for (int j = 0; j < RPT; ++j) {
            int r = row0 + j; if (r > M - 1) r = M - 1;   // clamp (stores are guarded)
            a[j] = *(const float4*)(A + (size_t)r * K + k0);
        }
#pragma unroll
        for (int kk = 0; kk < 4; ++kk) {
            float4 w = *(float4*)&wl[(k0 + kk) * N + col];
#pragma unroll
            for (int j = 0; j < RPT; ++j) {
                float av = (kk == 0) ? a[j].x : (kk == 1) ? a[j].y : (kk == 2) ? a[j].z : a[j].w;
                acc[j].x += av * w.x;
                acc[j].y += av * w.y;
                acc[j].z += av * w.z;
                acc[j].w += av * w.w;
            }
        }
    }

    float4 b4;
    if (BIAS) b4 = *(const float4*)(bias + col);
#pragma unroll
    for (int j = 0; j < RPT; ++j) {
        int r = row0 + j;
        if (r >= M) continue;
        float4 v = acc[j];
        if (RS) { float sc = rs[r]; v.x *= sc; v.y *= sc; v.z *= sc; v.w *= sc; }
        if (BIAS) { v.x += b4.x; v.y += b4.y; v.z += b4.z; v.w += b4.w; }
        if (OB) {
            uint32 lo = pack2bf(v.x, v.y);
            uint32 hi = pack2bf(v.z, v.w);
            uint32* op = (uint32*)((ushort16*)out + (size_t)r * N + col);
            op[0] = lo; op[1] = hi;
        } else {
            float* op = out + (size_t)r * N + col;
            if (ACCUM) {
                float4 o = *(const float4*)op;
                v.x += o.x; v.y += o.y; v.z += o.z; v.w += o.w;
            }
            *(float4*)op = v;
        }
    }
}

// ---------------------------------------------------------------------------
// GCN gather, bf16 input: out[r] = dinv[r]*(sum h[s] + h[r]) + bias  (fp32 out)
// DUALW: also write bf16 mirror of the output (for the following SAGE gather).
template <bool DUALW>
__global__ __launch_bounds__(256) void gcn_gather_bf(const ushort16* __restrict__ h,
                                                     const int* __restrict__ rowptr,
                                                     const int* __restrict__ col,
                                                     const float* __restrict__ dinv,
                                                     const float* __restrict__ bias,
                                                     float* __restrict__ out,
                                                     ushort16* __restrict__ mirror, int n) {
    int wid = threadIdx.x >> 6;
    int lane = threadIdx.x & 63;
    int r = blockIdx.x * 4 + wid;
    if (r >= n) return;
    const uint32* hp = (const uint32*)h;   // 2 bf16 per uint, 64 per row
    uint32 us = hp[(size_t)r * 64 + lane];
    float ax = bf16lo(us), ay = bf16hi(us);   // self-loop (pre-scaled)
    int e = rowptr[r], end = rowptr[r + 1];
    for (; e + 7 < end; e += 8) {
        int s0 = col[e],     s1 = col[e + 1], s2 = col[e + 2], s3 = col[e + 3];
        int s4 = col[e + 4], s5 = col[e + 5], s6 = col[e + 6], s7 = col[e + 7];
        uint32 u0 = hp[(size_t)s0 * 64 + lane];
        uint32 u1 = hp[(size_t)s1 * 64 + lane];
        uint32 u2 = hp[(size_t)s2 * 64 + lane];
        uint32 u3 = hp[(size_t)s3 * 64 + lane];
        uint32 u4 = hp[(size_t)s4 * 64 + lane];
        uint32 u5 = hp[(size_t)s5 * 64 + lane];
        uint32 u6 = hp[(size_t)s6 * 64 + lane];
        uint32 u7 = hp[(size_t)s7 * 64 + lane];
        ax += ((bf16lo(u0) + bf16lo(u1)) + (bf16lo(u2) + bf16lo(u3)))
            + ((bf16lo(u4) + bf16lo(u5)) + (bf16lo(u6) + bf16lo(u7)));
        ay += ((bf16hi(u0) + bf16hi(u1)) + (bf16hi(u2) + bf16hi(u3)))
            + ((bf16hi(u4) + bf16hi(u5)) + (bf16hi(u6) + bf16hi(u7)));
    }
    for (; e + 3 < end; e += 4) {
        int s0 = col[e], s1 = col[e + 1], s2 = col[e + 2], s3 = col[e + 3];
        uint32 u0 = hp[(size_t)s0 * 64 + lane];
        uint32 u1 = hp[(size_t)s1 * 64 + lane];
        uint32 u2 = hp[(size_t)s2 * 64 + lane];
        uint32 u3 = hp[(size_t)s3 * 64 + lane];
        ax += (bf16lo(u0) + bf16lo(u1)) + (bf16lo(u2) + bf16lo(u3));
        ay += (bf16hi(u0) + bf16hi(u1)) + (bf16hi(u2) + bf16hi(u3));
    }
    for (; e < end; ++e) {
        uint32 u = hp[(size_t)col[e] * 64 + lane];
        ax += bf16lo(u); ay += bf16hi(u);
    }
    float dv = dinv[r];
    float2 b = ((const float2*)bias)[lane];
    float ox = ax * dv + b.x;
    float oy = ay * dv + b.y;
    ((float2*)out)[(size_t)r * 64 + lane] = make_float2(ox, oy);
    if (DUALW) ((uint32*)mirror)[(size_t)r * 64 + lane] = pack2bf(ox, oy);
}

// SAGE mean gather, bf16 input: out[r] = (sum x[s]) * invcnt[r]  (fp32 out)
__global__ __launch_bounds__(256) void sage_gather_bf(const ushort16* __restrict__ x,
                                                      const int* __restrict__ rowptr,
                                                      const int* __restrict__ col,
                                                      const float* __restrict__ invcnt,
                                                      float* __restrict__ out, int n) {
    int wid = threadIdx.x >> 6;
    int lane = threadIdx.x & 63;
    int r = blockIdx.x * 4 + wid;
    if (r >= n) return;
    const uint32* xp = (const uint32*)x;
    float ax = 0.0f, ay = 0.0f;
    int e = rowptr[r], end = rowptr[r + 1];
    for (; e + 7 < end; e += 8) {
        int s0 = col[e],     s1 = col[e + 1], s2 = col[e + 2], s3 = col[e + 3];
        int s4 = col[e + 4], s5 = col[e + 5], s6 = col[e + 6], s7 = col[e + 7];
        uint32 u0 = xp[(size_t)s0 * 64 + lane];
        uint32 u1 = xp[(size_t)s1 * 64 + lane];
        uint32 u2 = xp[(size_t)s2 * 64 + lane];
        uint32 u3 = xp[(size_t)s3 * 64 + lane];
        uint32 u4 = xp[(size_t)s4 * 64 + lane];
        uint32 u5 = xp[(size_t)s5 * 64 + lane];
        uint32 u6 = xp[(size_t)s6 * 64 + lane];
        uint32 u7 = xp[(size_t)s7 * 64 + lane];
        ax += ((bf16lo(u0) + bf16lo(u1)) + (bf16lo(u2) + bf16lo(u3)))
            + ((bf16lo(u4) + bf16lo(u5)) + (bf16lo(u6) + bf16lo(u7)));
        ay += ((bf16hi(u0) + bf16hi(u1)) + (bf16hi(u2) + bf16hi(u3)))
            + ((bf16hi(u4) + bf16hi(u5)) + (bf16hi(u6) + bf16hi(u7)));
    }
    for (; e + 3 < end; e += 4) {
        int s0 = col[e], s1 = col[e + 1], s2 = col[e + 2], s3 = col[e + 3];
        uint32 u0 = xp[(size_t)s0 * 64 + lane];
        uint32 u1 = xp[(size_t)s1 * 64 + lane];
        uint32 u2 = xp[(size_t)s2 * 64 + lane];
        uint32 u3 = xp[(size_t)s3 * 64 + lane];
        ax += (bf16lo(u0) + bf16lo(u1)) + (bf16lo(u2) + bf16lo(u3));
        ay += (bf16hi(u0) + bf16hi(u1)) + (bf16hi(u2) + bf16hi(u3));
    }
    for (; e < end; ++e) {
        uint32 u = xp[(size_t)col[e] * 64 + lane];
        ax += bf16lo(u); ay += bf16hi(u);
    }
    float ic = invcnt[r];
    ((float2*)out)[(size_t)r * 64 + lane] = make_float2(ax * ic, ay * ic);
}

// ---------------------------------------------------------------------------
extern "C" void kernel_launch(void* const* d_in, const int* in_sizes, int n_in,
                              void* d_out, int out_size, void* d_ws, size_t ws_size,
                              hipStream_t stream) {
    const float* x_region = (const float*)d_in[0];   // [NR,128]
    const float* x_subject = (const float*)d_in[1];  // [NS,64]
    const int* rr_src = (const int*)d_in[2];
    const int* rr_dst = (const int*)d_in[3];
    const int* hs_src = (const int*)d_in[4];
    const int* hs_dst = (const int*)d_in[5];
    const float* Wg1 = (const float*)d_in[6];
    const float* bg1 = (const float*)d_in[7];
    const float* Wl1 = (const float*)d_in[8];
    const float* bl1 = (const float*)d_in[9];
    const float* Wr1 = (const float*)d_in[10];  // [64,128]
    const float* Wg2 = (const float*)d_in[11];
    const float* bg2 = (const float*)d_in[12];
    const float* Wl2 = (const float*)d_in[13];
    const float* bl2 = (const float*)d_in[14];
    const float* Wr2 = (const float*)d_in[15];  // [128,128]
    const float* Wout = (const float*)d_in[16]; // [128,64]
    const float* bout = (const float*)d_in[17]; // [64]
    float* out = (float*)d_out;

    // workspace layout
    float* ws = (float*)d_ws;
    float* A  = ws;                        // NR*128 floats worth of space:
    ushort16* hb  = (ushort16*)A;          //   first half:  h' bf16 [NR*128]
    ushort16* r1b = hb + (size_t)NR * 128; //   second half: r1 bf16 mirror [NR*128]
    float* C  = A + (size_t)NR * 128;      // NR*128  (r1, later r2) fp32
    float* SA = C + (size_t)NR * 128;      // NS*128  (sage mean)
    float* SB = SA + (size_t)NS * 128;     // NS*128  (s1)
    float* SC = SB + (size_t)NS * 128;     // NS*128  (s2)
    float* dinv   = SC + (size_t)NS * 128; // NR
    float* invcnt = dinv + NR;             // NS
    int* rrRowptr = (int*)(invcnt + NS);   // NR+1
    int* rrCursor = rrRowptr + NR + 1;     // NR (counts -> cursor)
    int* rrCol    = rrCursor + NR;         // ERR_E
    int* hsRowptr = rrCol + ERR_E;         // NS+1
    int* hsCursor = hsRowptr + NS + 1;     // NS
    int* hsCol    = hsCursor + NS;         // EHS_E
    int* rrPart   = hsCol + EHS_E;         // 64 partials
    int* hsPart   = rrPart + 64;           // 64 partials
    ushort16* xrb = (ushort16*)(hsPart + 64); // NR*128 bf16 mirror of x_region

    const int TB = 256;
    constexpr int RR_BLKS = (NR + 1023) / 1024;   // 49
    constexpr int HS_BLKS = (NS + 1023) / 1024;   // 8

    // ---------------- CSR build + x_region bf16 mirror ----------------
    hipMemsetAsync(rrCursor, 0, (size_t)NR * sizeof(int), stream);
    hipMemsetAsync(hsCursor, 0, (size_t)NS * sizeof(int), stream);
    count_edges_both<<<(ERR_E + EHS_E + TB - 1) / TB, TB, 0, stream>>>(
        rr_dst, hs_dst, rrCursor, hsCursor);
    cast_bf<<<(NR * 128 / 4 + TB - 1) / TB, TB, 0, stream>>>(
        (const float4*)x_region, xrb, NR * 128 / 4);
    block_sums<<<RR_BLKS, 1024, 0, stream>>>(rrCursor, rrPart, NR);
    block_sums<<<HS_BLKS, 1024, 0, stream>>>(hsCursor, hsPart, NS);
    scan_partials<<<1, 64, 0, stream>>>(rrPart, RR_BLKS);
    scan_partials<<<1, 64, 0, stream>>>(hsPart, HS_BLKS);
    scan_finalize<0><<<RR_BLKS, 1024, 0, stream>>>(rrCursor, rrPart, rrRowptr, dinv, NR);
    scan_finalize<1><<<HS_BLKS, 1024, 0, stream>>>(hsCursor, hsPart, hsRowptr, invcnt, NS);
    fill_csr_both<<<(ERR_E + EHS_E + TB - 1) / TB, TB, 0, stream>>>(
        rr_src, rr_dst, rrCursor, rrCol, hs_src, hs_dst, hsCursor, hsCol);

    // ---------------- Layer 1 ----------------
    // h1' = (x_region @ Wg1) * dinv -> hb (bf16)
    gemm_lds<128, 128, false, true, false, true><<<(NR + 63) / 64, TB, 0, stream>>>(
        x_region, Wg1, nullptr, dinv, (float*)hb, NR);
    // r1 = dinv*(gather(hb)+self) + bg1 -> C (fp32) + r1b (bf16 mirror)
    gcn_gather_bf<true><<<(NR + 3) / 4, TB, 0, stream>>>(
        hb, rrRowptr, rrCol, dinv, bg1, C, r1b, NR);
    // SAGE1 mean of x_region (bf16 mirror) -> SA
    sage_gather_bf<<<(NS + 3) / 4, TB, 0, stream>>>(xrb, hsRowptr, hsCol, invcnt, SA, NS);
    // s1 = SA @ Wl1 + bl1 -> SB ; then SB += x_subject @ Wr1
    gemm_lds<128, 128, true, false, false, false><<<(NS + 63) / 64, TB, 0, stream>>>(
        SA, Wl1, bl1, nullptr, SB, NS);
    gemm_lds<128, 64, false, false, true, false><<<(NS + 63) / 64, TB, 0, stream>>>(
        x_subject, Wr1, nullptr, nullptr, SB, NS);

    // ---------------- Layer 2 ----------------
    // SAGE2 mean of r1 (bf16 mirror) -> SA
    sage_gather_bf<<<(NS + 3) / 4, TB, 0, stream>>>(r1b, hsRowptr, hsCol, invcnt, SA, NS);
    // s2 = SA @ Wl2 + bl2 -> SC ; then SC += SB @ Wr2
    gemm_lds<128, 128, true, false, false, false><<<(NS + 63) / 64, TB, 0, stream>>>(
        SA, Wl2, bl2, nullptr, SC, NS);
    gemm_lds<128, 128, false, false, true, false><<<(NS + 63) / 64, TB, 0, stream>>>(
        SB, Wr2, nullptr, nullptr, SC, NS);
    // h2' = (r1 @ Wg2) * dinv -> hb (bf16)   (r1 fp32 still in C)
    gemm_lds<128, 128, false, true, false, true><<<(NR + 63) / 64, TB, 0, stream>>>(
        C, Wg2, nullptr, dinv, (float*)hb, NR);
    // r2 = dinv*(gather(hb)+self) + bg2 -> C (overwrite r1)
    gcn_gather_bf<false><<<(NR + 3) / 4, TB, 0, stream>>>(
        hb, rrRowptr, rrCol, dinv, bg2, C, nullptr, NR);

    // ---------------- Output ----------------
    gemm_lds<64, 128, true, false, false, false><<<(NR + 63) / 64, TB, 0, stream>>>(
        C, Wout, bout, nullptr, out, NR);
    gemm_lds<64, 128, true, false, false, false><<<(NS + 63) / 64, TB, 0, stream>>>(
        SC, Wout, bout, nullptr, out + (size_t)NR * 64, NS);
}